// Round 9
// baseline (9542.224 us; speedup 1.0000x reference)
//
#include <hip/hip_runtime.h>

typedef unsigned short u16;
typedef unsigned int u32;
typedef unsigned long long u64;
typedef __bf16 bfrag __attribute__((ext_vector_type(8)));
typedef float v4f __attribute__((ext_vector_type(4)));

#define DI __device__ __forceinline__

DI float bf2f(u16 b){ union{u32 u; float f;} c; c.u = ((u32)b)<<16; return c.f; }
DI u16 f2bf(float f){ union{float f; u32 u;} c; c.f=f; u32 u=c.u; return (u16)((u + 0x7FFFu + ((u>>16)&1u))>>16); }
DI float sigm(float x){ return 1.0f/(1.0f+__expf(-x)); }
DI float tanhf_(float x){ float a=fabsf(x); float e=__expf(2.0f*a); float r=1.0f-2.0f/(e+1.0f); return x<0.0f? -r : r; }

// ---------------- fp32 -> (hi,lo) bf16 split
__global__ __launch_bounds__(256) void k_cvt2(const float* __restrict__ src, u16* __restrict__ hi,
                                              u16* __restrict__ lo, u32 n){
  u32 i = blockIdx.x*256u + threadIdx.x;
  if (i < n){ float v = src[i]; u16 h = f2bf(v); hi[i] = h; lo[i] = f2bf(v - bf2f(h)); }
}

// ---------------- conv1 (batch quarter): x fp32 -> y1q fp32 (256,4,192,28)
__global__ __launch_bounds__(256) void k_conv1(const float* __restrict__ x, const float* __restrict__ w,
                                               const float* __restrict__ bias, float* __restrict__ y1q, u32 bbase){
  u32 gid = blockIdx.x*256u + threadIdx.x;
  u32 bl = gid/192u, oy = gid - bl*192u;
  const float* xb = x + (u64)(bbase+bl)*10752u;
  float win[4][30];
  #pragma unroll
  for (int rr=0; rr<4; rr++){
    int iy = 2*(int)oy - 1 + rr;
    bool vy = (u32)iy < 384u;
    #pragma unroll
    for (int cc=0; cc<30; cc++){
      int ix = cc - 1;
      win[rr][cc] = (vy && (u32)ix < 28u) ? xb[iy*28 + ix] : 0.0f;
    }
  }
  for (int co=0; co<4; co++){
    float wf[9];
    #pragma unroll
    for (int j=0;j<9;j++) wf[j] = w[co*9+j];
    float bc = bias[co];
    float* outp = y1q + ((u64)(bl*4u+co)*192u + oy)*28u;
    #pragma unroll
    for (int ox=0; ox<28; ox++){
      float m = 0.0f;
      #pragma unroll
      for (int py=0; py<2; py++){
        float s = bc;
        #pragma unroll
        for (int dy=0; dy<3; dy++)
          #pragma unroll
          for (int dx=0; dx<3; dx++)
            s += win[py+dy][ox+dx]*wf[dy*3+dx];
        m = fmaxf(m, s);
      }
      outp[ox] = m;
    }
  }
}

// ---------------- conv2 (quarter): y1q -> y2q fp32 (256,16,96,14)
__global__ __launch_bounds__(256) void k_conv2(const float* __restrict__ y1q, const float* __restrict__ w,
                                               const float* __restrict__ bias, float* __restrict__ y2q){
  u32 gid = blockIdx.x*256u + threadIdx.x;
  u32 bl = gid/96u, oy = gid - bl*96u;
  const float* inb = y1q + (u64)bl*21504u;
  for (int co=0; co<16; co++){
    float acc[14][4];
    #pragma unroll
    for (int i=0;i<14;i++){ acc[i][0]=0.f;acc[i][1]=0.f;acc[i][2]=0.f;acc[i][3]=0.f; }
    for (int ci=0; ci<4; ci++){
      float win[4][30];
      const float* pl = inb + ci*5376;
      #pragma unroll
      for (int rr=0; rr<4; rr++){
        int iy = 2*(int)oy - 1 + rr;
        bool vy = (u32)iy < 192u;
        #pragma unroll
        for (int cc=0; cc<30; cc++){
          int ix = cc-1;
          win[rr][cc] = (vy && (u32)ix<28u) ? pl[iy*28+ix] : 0.0f;
        }
      }
      float wf[9];
      #pragma unroll
      for (int j=0;j<9;j++) wf[j] = w[(co*4+ci)*9+j];
      #pragma unroll
      for (int ox=0; ox<14; ox++){
        #pragma unroll
        for (int py=0; py<2; py++)
          #pragma unroll
          for (int px=0; px<2; px++){
            float s = acc[ox][py*2+px];
            #pragma unroll
            for (int dy=0; dy<3; dy++)
              #pragma unroll
              for (int dx=0; dx<3; dx++)
                s += win[py+dy][2*ox+px+dx]*wf[dy*3+dx];
            acc[ox][py*2+px] = s;
          }
      }
    }
    float bc = bias[co];
    float* outp = y2q + ((u64)(bl*16u+co)*96u + oy)*14u;
    #pragma unroll
    for (int ox=0; ox<14; ox++){
      float m = fmaxf(fmaxf(acc[ox][0],acc[ox][1]), fmaxf(acc[ox][2],acc[ox][3])) + bc;
      outp[ox] = fmaxf(m, 0.0f);
    }
  }
}

// ---------------- conv3 (quarter): y2q -> y3 fp32 (1024,16,32,7)
__global__ __launch_bounds__(256) void k_conv3(const float* __restrict__ y2q, const float* __restrict__ w,
                                               const float* __restrict__ bias, float* __restrict__ y3, u32 bbase){
  u32 gid = blockIdx.x*256u + threadIdx.x;
  u32 bl = gid/64u, r = gid - bl*64u;
  u32 oy = r>>1, cg = r&1u;
  const float* inb = y2q + (u64)bl*21504u;
  for (int co8=0; co8<8; co8++){
    int co = (int)cg*8 + co8;
    float acc[7][6];
    #pragma unroll
    for (int i=0;i<7;i++){
      #pragma unroll
      for (int j=0;j<6;j++) acc[i][j]=0.0f;
    }
    for (int ci=0; ci<16; ci++){
      float win[5][16];
      const float* pl = inb + ci*1344;
      #pragma unroll
      for (int rr=0; rr<5; rr++){
        int iy = 3*(int)oy - 1 + rr;
        bool vy = (u32)iy < 96u;
        #pragma unroll
        for (int cc=0; cc<16; cc++){
          int ix = cc-1;
          win[rr][cc] = (vy && (u32)ix<14u) ? pl[iy*14+ix] : 0.0f;
        }
      }
      float wf[9];
      #pragma unroll
      for (int j=0;j<9;j++) wf[j] = w[(co*16+ci)*9+j];
      #pragma unroll
      for (int ox=0; ox<7; ox++){
        #pragma unroll
        for (int py=0; py<3; py++)
          #pragma unroll
          for (int px=0; px<2; px++){
            float s = acc[ox][py*2+px];
            #pragma unroll
            for (int dy=0; dy<3; dy++)
              #pragma unroll
              for (int dx=0; dx<3; dx++)
                s += win[py+dy][2*ox+px+dx]*wf[dy*3+dx];
            acc[ox][py*2+px] = s;
          }
      }
    }
    float bc = bias[co];
    float* outp = y3 + ((u64)((bbase+bl)*16u+(u32)co)*32u + oy)*7u;
    #pragma unroll
    for (int ox=0; ox<7; ox++){
      float m = acc[ox][0];
      #pragma unroll
      for (int j=1;j<6;j++) m = fmaxf(m, acc[ox][j]);
      outp[ox] = fmaxf(m + bc, 0.0f);
    }
  }
}

// ---------------- conv4 (full): y3 -> y5 fp32 (1024,32,224)  [ad = ox*32+co]
__global__ __launch_bounds__(256) void k_conv4(const float* __restrict__ y3, const float* __restrict__ w,
                                               const float* __restrict__ bias, float* __restrict__ y5){
  u32 gid = blockIdx.x*256u + threadIdx.x;
  u32 b = gid/128u, r = gid - b*128u;
  u32 oy = r>>2, cg = r&3u;
  u32 co0 = cg*8u;
  const float* inb = y3 + (u64)b*3584u;
  float acc[8][7];
  #pragma unroll
  for (int i=0;i<8;i++){
    #pragma unroll
    for (int j=0;j<7;j++) acc[i][j]=0.0f;
  }
  for (int ci=0; ci<16; ci++){
    float win[3][9];
    const float* pl = inb + ci*224;
    #pragma unroll
    for (int rr=0; rr<3; rr++){
      int iy = (int)oy - 1 + rr;
      bool vy = (u32)iy < 32u;
      #pragma unroll
      for (int cc=0; cc<9; cc++){
        int ix = cc-1;
        win[rr][cc] = (vy && (u32)ix<7u) ? pl[iy*7+ix] : 0.0f;
      }
    }
    #pragma unroll
    for (int co=0; co<8; co++){
      float wf[9];
      #pragma unroll
      for (int j=0;j<9;j++) wf[j] = w[((co0+co)*16u+(u32)ci)*9u+j];
      #pragma unroll
      for (int ox=0; ox<7; ox++){
        float s = acc[co][ox];
        #pragma unroll
        for (int dy=0; dy<3; dy++)
          #pragma unroll
          for (int dx=0; dx<3; dx++)
            s += win[dy][ox+dx]*wf[dy*3+dx];
        acc[co][ox] = s;
      }
    }
  }
  #pragma unroll
  for (int co=0; co<8; co++){
    float bc = bias[co0+co];
    #pragma unroll
    for (int ox=0; ox<7; ox++)
      y5[((u64)b*32u + oy)*224u + (u32)ox*32u + (co0+co)] = fmaxf(acc[co][ox] + bc, 0.0f);
  }
}

// ---------------- encoder LSTM, split-bf16 MFMA, persistent: 64 WGs x 16 rows, 32 steps
__global__ __launch_bounds__(512) void k_enc(const u16* __restrict__ WihHi, const u16* __restrict__ WihLo,
                                             const u16* __restrict__ WhhHi, const u16* __restrict__ WhhLo,
                                             const float* __restrict__ bih, const float* __restrict__ bhh,
                                             const float* __restrict__ y5, const float* __restrict__ h0,
                                             const float* __restrict__ c0, float* __restrict__ y8){
  __shared__ __align__(16) u16 xhi[16*248], xlo[16*248];
  __shared__ __align__(16) u16 hhi[16*248], hlo[16*248];
  __shared__ __align__(16) float gsh[8*904];
  __shared__ __align__(16) float bsh[896];
  u32 tid = threadIdx.x, w = tid>>6, lane = tid&63u, nl = lane&15u, quad = lane>>4;
  u32 b0 = blockIdx.x*16u;
  for (u32 it=tid; it<896u; it+=512u) bsh[it] = bih[it] + bhh[it];
  for (u32 it=tid; it<3584u; it+=512u){
    u32 r = it/224u, c = it - r*224u;
    float v = h0[c]; u16 hb = f2bf(v);
    hhi[r*248u+c] = hb; hlo[r*248u+c] = f2bf(v - bf2f(hb));
  }
  float creg[8];
  #pragma unroll
  for (int hh=0; hh<2; hh++){
    #pragma unroll
    for (int p=0; p<4; p++){
      u32 l = (u32)p*512u + tid;
      if (l < 1792u){ u32 c = l % 224u; creg[hh*4+p] = c0[c]; }
    }
  }
  __syncthreads();
  for (int t=0; t<32; t++){
    #pragma unroll
    for (int i=0;i<7;i++){
      u32 item = (u32)i*512u + tid;
      u32 r = item/224u, c = item - r*224u;
      float v = y5[((u64)(b0+r)*32u + (u32)t)*224u + c];
      u16 hb = f2bf(v);
      xhi[r*248u+c] = hb; xlo[r*248u+c] = f2bf(v - bf2f(hb));
    }
    __syncthreads();   // S1: xs ready; prev gsh reads + h writes done
    v4f acc[7] = {};
    #pragma unroll
    for (int kt=0; kt<7; kt++){
      u32 ao = nl*248u + (u32)kt*32u + quad*8u;
      bfrag axh = *(const bfrag*)&xhi[ao];
      bfrag axl = *(const bfrag*)&xlo[ao];
      bfrag ahh = *(const bfrag*)&hhi[ao];
      bfrag ahl = *(const bfrag*)&hlo[ao];
      #pragma unroll
      for (int nt=0; nt<7; nt++){
        u64 off = (u64)(w*112u + (u32)nt*16u + nl)*224u + (u32)kt*32u + quad*8u;
        bfrag bIh = *(const bfrag*)&WihHi[off];
        bfrag bIl = *(const bfrag*)&WihLo[off];
        bfrag bHh = *(const bfrag*)&WhhHi[off];
        bfrag bHl = *(const bfrag*)&WhhLo[off];
        acc[nt] = __builtin_amdgcn_mfma_f32_16x16x32_bf16(axh, bIh, acc[nt], 0,0,0);
        acc[nt] = __builtin_amdgcn_mfma_f32_16x16x32_bf16(axl, bIh, acc[nt], 0,0,0);
        acc[nt] = __builtin_amdgcn_mfma_f32_16x16x32_bf16(axh, bIl, acc[nt], 0,0,0);
        acc[nt] = __builtin_amdgcn_mfma_f32_16x16x32_bf16(ahh, bHh, acc[nt], 0,0,0);
        acc[nt] = __builtin_amdgcn_mfma_f32_16x16x32_bf16(ahl, bHh, acc[nt], 0,0,0);
        acc[nt] = __builtin_amdgcn_mfma_f32_16x16x32_bf16(ahh, bHl, acc[nt], 0,0,0);
      }
    }
    // two half-phases: rows [0,8) then [8,16)
    #pragma unroll
    for (int hh=0; hh<2; hh++){
      if ((quad>>1) == (u32)hh){
        #pragma unroll
        for (int nt=0; nt<7; nt++)
          #pragma unroll
          for (int rg=0; rg<4; rg++){
            u32 col = w*112u + (u32)nt*16u + nl;
            gsh[((quad&1u)*4u+(u32)rg)*904u + col] = acc[nt][rg] + bsh[col];
          }
      }
      __syncthreads();   // gsh half ready
      #pragma unroll
      for (int p=0; p<4; p++){
        u32 l = (u32)p*512u + tid;
        if (l < 1792u){
          u32 rl = l/224u, c = l - rl*224u;
          u32 r = (u32)hh*8u + rl;
          float gi = gsh[rl*904u + c];
          float gf = gsh[rl*904u + 224u + c];
          float gg = gsh[rl*904u + 448u + c];
          float go = gsh[rl*904u + 672u + c];
          float cv = sigm(gf)*creg[hh*4+p] + sigm(gi)*tanhf_(gg);
          float hv = sigm(go)*tanhf_(cv);
          creg[hh*4+p] = cv;
          u16 hb = f2bf(hv);
          hhi[r*248u + c] = hb;
          hlo[r*248u + c] = f2bf(hv - bf2f(hb));
          y8[((u64)(b0+r)*32u + (u32)t)*224u + c] = hv;
        }
      }
      if (hh==0) __syncthreads();  // half-0 gsh reads done before half-1 overwrites
    }
  }
}

// ---------------- decoder w/ attention, split-bf16 MFMA, persistent: 64 WGs x 16 rows, 25 steps
__global__ __launch_bounds__(512) void k_dec(const float* __restrict__ y8,
    const float* __restrict__ attw, const float* __restrict__ attb,
    const u16* __restrict__ WihHi, const u16* __restrict__ WihLo,
    const u16* __restrict__ WhhHi, const u16* __restrict__ WhhLo,
    const float* __restrict__ bih, const float* __restrict__ bhh,
    const float* __restrict__ outw, const float* __restrict__ outb,
    float* __restrict__ outp){
  __shared__ __align__(16) u16 Ahi[16*504], Alo[16*504];   // A-tile: k<224 ctx | 224..480 h
  __shared__ __align__(16) float hdec[16*260];
  __shared__ __align__(16) float esc[16*33];
  __shared__ __align__(16) float alp[16*33];
  __shared__ __align__(16) float bshd[1024];
  u32 tid=threadIdx.x, w=tid>>6, lane=tid&63u, nl=lane&15u, quad=lane>>4;
  u32 b0 = blockIdx.x*16u;
  for (u32 it=tid; it<1024u; it+=512u) bshd[it] = bih[it] + bhh[it];
  for (u32 it=tid; it<4160u; it+=512u) hdec[it]=0.0f;
  for (u32 it=tid; it<4096u; it+=512u){
    u32 r=it>>8, c=it&255u;
    Ahi[r*504u+224u+c]=0; Alo[r*504u+224u+c]=0;
  }
  {
    u32 r=tid>>5, t=tid&31u;
    const float* yr = y8 + ((u64)(b0+r)*32u + t)*224u;
    const float* we = attw + 256;
    float s=0.0f;
    #pragma unroll 8
    for (int j=0;j<224;j++) s += yr[j]*we[j];
    esc[r*33u+t] = s + attb[0];
  }
  u32 ncol[8];
  #pragma unroll
  for (int nt=0; nt<8; nt++)
    ncol[nt] = (u32)(nt>>1)*256u + w*32u + (u32)(nt&1)*16u + nl;
  float cst[2][4];
  #pragma unroll
  for (int q=0;q<2;q++){ cst[q][0]=0.f;cst[q][1]=0.f;cst[q][2]=0.f;cst[q][3]=0.f; }
  __syncthreads();
  for (int s=0; s<25; s++){
    { // attention scores + softmax
      u32 r=tid>>5, t=tid&31u;
      float part=0.0f;
      #pragma unroll
      for (int qq=0; qq<8; qq++){
        u32 c = t + (u32)qq*32u;
        part += hdec[r*260u+c]*attw[c];
      }
      #pragma unroll
      for (int off=16; off; off>>=1) part += __shfl_xor(part, off, 32);
      float sv = esc[r*33u+t] + part;
      float mx = sv;
      #pragma unroll
      for (int off=16; off; off>>=1) mx = fmaxf(mx, __shfl_xor(mx, off, 32));
      float e = __expf(sv-mx);
      float ssum = e;
      #pragma unroll
      for (int off=16; off; off>>=1) ssum += __shfl_xor(ssum, off, 32);
      alp[r*33u+t] = e/ssum;
    }
    __syncthreads();
    // ctx (fp32) -> A-tile hi/lo
    #pragma unroll
    for (int i=0;i<7;i++){
      u32 item = (u32)i*512u + tid;
      u32 rr = item/224u, c = item - rr*224u;
      const float* yb = y8 + (u64)(b0+rr)*32u*224u + c;
      float a0=0.0f;
      #pragma unroll
      for (int tt=0; tt<32; tt++) a0 += alp[rr*33u+(u32)tt]*yb[(u32)tt*224u];
      u16 hb = f2bf(a0);
      Ahi[rr*504u + c] = hb;
      Alo[rr*504u + c] = f2bf(a0 - bf2f(hb));
    }
    __syncthreads();
    // gates = [ctx|h] @ [Wih|Whh]^T, 3-term split
    v4f acc[8] = {};
    #pragma unroll
    for (int kt=0; kt<15; kt++){
      u32 ao = nl*504u + (u32)kt*32u + quad*8u;
      bfrag afh = *(const bfrag*)&Ahi[ao];
      bfrag afl = *(const bfrag*)&Alo[ao];
      #pragma unroll
      for (int nt=0; nt<8; nt++){
        bfrag bh, bl;
        if (kt<7){
          u64 off = (u64)ncol[nt]*224u + (u32)kt*32u + quad*8u;
          bh = *(const bfrag*)&WihHi[off]; bl = *(const bfrag*)&WihLo[off];
        } else {
          u64 off = (u64)ncol[nt]*256u + (u32)(kt-7)*32u + quad*8u;
          bh = *(const bfrag*)&WhhHi[off]; bl = *(const bfrag*)&WhhLo[off];
        }
        acc[nt] = __builtin_amdgcn_mfma_f32_16x16x32_bf16(afh, bh, acc[nt], 0,0,0);
        acc[nt] = __builtin_amdgcn_mfma_f32_16x16x32_bf16(afl, bh, acc[nt], 0,0,0);
        acc[nt] = __builtin_amdgcn_mfma_f32_16x16x32_bf16(afh, bl, acc[nt], 0,0,0);
      }
    }
    __syncthreads();
    // in-register LSTM cell (M1: row=quad*4+rg, col=nl — verified in-situ R7/R8)
    #pragma unroll
    for (int q=0; q<2; q++){
      u32 c = w*32u + (u32)q*16u + nl;
      #pragma unroll
      for (int rg=0; rg<4; rg++){
        u32 row = quad*4u + (u32)rg;
        float gi = acc[0+q][rg] + bshd[c];
        float gf = acc[2+q][rg] + bshd[256u+c];
        float gg = acc[4+q][rg] + bshd[512u+c];
        float go = acc[6+q][rg] + bshd[768u+c];
        float cv = sigm(gf)*cst[q][rg] + sigm(gi)*tanhf_(gg);
        float hv = sigm(go)*tanhf_(cv);
        cst[q][rg] = cv;
        hdec[row*260u + c] = hv;
        u16 hb = f2bf(hv);
        Ahi[row*504u + 224u + c] = hb;
        Alo[row*504u + 224u + c] = f2bf(hv - bf2f(hb));
      }
    }
    __syncthreads();
    // out projection: 16 rows x 29 vocab, fp32 OUTPUT (B, VOCAB, OUT_LEN)
    if (tid < 464u){
      u32 rr = tid/29u, v = tid - rr*29u;
      const float* hr = &hdec[rr*260u];
      const float* wr = outw + (u64)v*256u;
      float a2 = 0.0f;
      #pragma unroll 8
      for (int j=0;j<256;j++) a2 += hr[j]*wr[j];
      outp[((u64)(b0+rr)*29u + v)*25u + (u32)s] = a2 + outb[v];
    }
    __syncthreads();
  }
}

extern "C" void kernel_launch(void* const* d_in, const int* in_sizes, int n_in,
                              void* d_out, int out_size, void* d_ws, size_t ws_size,
                              hipStream_t stream){
  (void)in_sizes; (void)n_in; (void)out_size; (void)ws_size;
  const float* x    = (const float*)d_in[0];
  const float* c1w  = (const float*)d_in[1];
  const float* c1b  = (const float*)d_in[2];
  const float* c2w  = (const float*)d_in[3];
  const float* c2b  = (const float*)d_in[4];
  const float* c3w  = (const float*)d_in[5];
  const float* c3b  = (const float*)d_in[6];
  const float* c4w  = (const float*)d_in[7];
  const float* c4b  = (const float*)d_in[8];
  const float* h0   = (const float*)d_in[9];
  const float* c0   = (const float*)d_in[10];
  const float* lWih = (const float*)d_in[11];
  const float* lWhh = (const float*)d_in[12];
  const float* lbih = (const float*)d_in[13];
  const float* lbhh = (const float*)d_in[14];
  const float* attw = (const float*)d_in[15];
  const float* attb = (const float*)d_in[16];
  const float* dWih = (const float*)d_in[17];
  const float* dWhh = (const float*)d_in[18];
  const float* dbih = (const float*)d_in[19];
  const float* dbhh = (const float*)d_in[20];
  const float* outw = (const float*)d_in[21];
  const float* outb = (const float*)d_in[22];
  float* out = (float*)d_out;   // reference output dtype is float32
  char* ws = (char*)d_ws;
  // workspace (peak 62,291,968 B), with overlaps:
  //   y1q [0,22.02M) y2q [22.02,44.04M) y3 [44.04,58.72M)   (conv phase)
  //   y5  [0,29.36M)   (written by conv4 after y1q/y2q dead)
  //   y8  [29.36,58.72M) (written by k_enc after y2q/y3 dead)
  float* y1q = (float*)(ws);
  float* y2q = (float*)(ws + 22020096ull);
  float* y3  = (float*)(ws + 44040192ull);
  float* y5  = (float*)(ws);
  float* y8  = (float*)(ws + 29360128ull);
  u16* lWihHi = (u16*)(ws + 58720256ull);
  u16* lWihLo = (u16*)(ws + 59121664ull);
  u16* lWhhHi = (u16*)(ws + 59523072ull);
  u16* lWhhLo = (u16*)(ws + 59924480ull);
  u16* dWihHi = (u16*)(ws + 60325888ull);
  u16* dWihLo = (u16*)(ws + 60784640ull);
  u16* dWhhHi = (u16*)(ws + 61243392ull);
  u16* dWhhLo = (u16*)(ws + 61767680ull);

  k_cvt2<<<dim3(784),  dim3(256), 0, stream>>>(lWih, lWihHi, lWihLo, 200704u);
  k_cvt2<<<dim3(784),  dim3(256), 0, stream>>>(lWhh, lWhhHi, lWhhLo, 200704u);
  k_cvt2<<<dim3(896),  dim3(256), 0, stream>>>(dWih, dWihHi, dWihLo, 229376u);
  k_cvt2<<<dim3(1024), dim3(256), 0, stream>>>(dWhh, dWhhHi, dWhhLo, 262144u);
  for (u32 q=0; q<4; q++){
    k_conv1<<<dim3(192), dim3(256), 0, stream>>>(x, c1w, c1b, y1q, q*256u);
    k_conv2<<<dim3(96),  dim3(256), 0, stream>>>(y1q, c2w, c2b, y2q);
    k_conv3<<<dim3(64),  dim3(256), 0, stream>>>(y2q, c3w, c3b, y3, q*256u);
  }
  k_conv4<<<dim3(512), dim3(256), 0, stream>>>(y3, c4w, c4b, y5);
  k_enc  <<<dim3(64), dim3(512), 0, stream>>>(lWihHi, lWihLo, lWhhHi, lWhhLo, lbih, lbhh, y5, h0, c0, y8);
  k_dec  <<<dim3(64), dim3(512), 0, stream>>>(y8, attw, attb, dWihHi, dWihLo, dWhhHi, dWhhLo,
                                              dbih, dbhh, outw, outb, out);
}